// Round 12
// baseline (101.556 us; speedup 1.0000x reference)
//
#include <hip/hip_runtime.h>

#define BB 16
#define QQ 1000
#define NH 8
#define LTOTAL 5440
#define MQ (BB*QQ)      // 16000
#define MV (BB*LTOTAL)  // 87040
#define NVBLK ((MV/128)*2)   // 1360 value-GEMM blocks
#define NOBLK ((MQ/128)*3)   // 375 offattn-GEMM blocks

typedef __bf16 bf16x8 __attribute__((ext_vector_type(8)));
typedef float  f32x4  __attribute__((ext_vector_type(4)));

template <int N> struct IC { static constexpr int v = N; };

__device__ __forceinline__ unsigned short f2bf(float f) {
  unsigned u = __builtin_bit_cast(unsigned, f);
  u += 0x7fffu + ((u >> 16) & 1u);
  return (unsigned short)(u >> 16);
}
__device__ __forceinline__ float b2f_lo(unsigned u) {
  return __builtin_bit_cast(float, u << 16);
}
__device__ __forceinline__ float b2f_hi(unsigned u) {
  return __builtin_bit_cast(float, u & 0xffff0000u);
}

__device__ __forceinline__ void gload16(const void* g, void* l) {
  __builtin_amdgcn_global_load_lds(
      (const __attribute__((address_space(1))) unsigned int*)g,
      (__attribute__((address_space(3))) unsigned int*)l, 16, 0, 0);
}

// lgkmcnt(0) + raw barrier; vmcnt deliberately left alone (reg-staged loads
// are tracked precisely per-register by the compiler).
__device__ __forceinline__ void pipe_barrier() {
  asm volatile("s_waitcnt lgkmcnt(0)" ::: "memory");
  __builtin_amdgcn_sched_barrier(0);
  __builtin_amdgcn_s_barrier();
  __builtin_amdgcn_sched_barrier(0);
}

// ---------------- prep: weights -> [panel][k_octet][n] granule layout + biases --
__global__ __launch_bounds__(256) void prep_k(const float* __restrict__ Wv,
                                              const float* __restrict__ Wo,
                                              const float* __restrict__ Wa,
                                              const float* __restrict__ Wout,
                                              const float* __restrict__ bo,
                                              const float* __restrict__ ba,
                                              unsigned short* __restrict__ WvS,  // 2 panels
                                              unsigned short* __restrict__ WcS,  // 3 panels
                                              unsigned short* __restrict__ WoS,  // 2 panels
                                              float* __restrict__ bcat) {
  int i = blockIdx.x * 256 + threadIdx.x;
  if (i < 28672) {
    const float* src;
    unsigned short* dst;
    int g, srcN;
    if (i < 8192)       { g = i;         dst = WvS; src = Wv;   srcN = 256; }
    else if (i < 20480) { g = i - 8192;  dst = WcS; src = Wo;   srcN = 256; }
    else                { g = i - 20480; dst = WoS; src = Wout; srcN = 256; }
    int panel = g >> 12, ko = (g >> 7) & 31, row = g & 127;
    int kbase = ko * 8;
    int n = panel * 128 + row;
    if (dst == WcS && panel == 2) { src = Wa; srcN = 128; n = row; }
    bf16x8 r;
#pragma unroll
    for (int e = 0; e < 8; e++) r[e] = (__bf16)src[(size_t)(kbase + e) * srcN + n];
    *(bf16x8*)(dst + (size_t)g * 8) = r;
  } else if (i < 29056) {
    int j = i - 28672;
    bcat[j] = j < 256 ? bo[j] : ba[j - 256];
  }
}

// ---------------- fused value+offattn GEMM: all-register depth-3 staging -------
// bid < NVBLK : value = input_flatten @ WvS + bv -> bf16 [MV,256]
// else        : offattn = query @ WcS + bcat     -> fp32 [MQ,384]
// Per step t: issue reg-loads(t+3) [A fp32 4x16B + B 2x16B]; compute(t) from
// LDS; cvt+ds_write(t+1) -- its register dep-wait covers loads issued TWO full
// iterations earlier (~600+cy); one lgkm barrier. ZERO global_load_lds here,
// so the compiler's vmcnt tracking is exact per-register (no conservative
// drains possible). XCD swizzle + swapped-operand vectorized epilogue from R10.
__global__ __launch_bounds__(256, 3) void gemmf_k(const float* __restrict__ Aval,
                                                  const float* __restrict__ Aoff,
                                                  const unsigned short* __restrict__ WvS,
                                                  const unsigned short* __restrict__ WcS,
                                                  const float* __restrict__ bv,
                                                  const float* __restrict__ bcat,
                                                  unsigned short* __restrict__ Cval,
                                                  float* __restrict__ Coff) {
  constexpr int K = 256, NT = 8;
  constexpr int NWG = NVBLK + NOBLK;           // 1735
  constexpr int QC = NWG / 8, RC = NWG % 8;    // 216, 7
  __shared__ char lds[4 * 8192];               // A 2 stages + B 2 stages
  char* As = lds;
  char* Bs = lds + 2 * 8192;

  int orig = blockIdx.x;
  int xcd = orig & 7, pos = orig >> 3;
  int bid = (xcd < RC ? xcd * (QC + 1) : RC * (QC + 1) + (xcd - RC) * QC) + pos;

  bool isVal = bid < NVBLK;
  int vbid = isVal ? bid : bid - NVBLK;
  int ntiles = isVal ? 2 : 3;
  const float* Av = isVal ? Aval : Aoff;
  const unsigned short* WS = isVal ? WvS : WcS;
  const float* bias = isVal ? bv : bcat;

  int tid = threadIdx.x, wave = tid >> 6, lane = tid & 63;
  int mt = vbid / ntiles, nt = vbid - mt * ntiles;
  int r16 = lane & 15, kg = lane >> 4;
  int wm = wave >> 1, wn = wave & 1;
  int arow = tid >> 1, ahalf = tid & 1;

  const unsigned short* Bpanel = WS + (size_t)nt * (NT * 512 * 8);
  const float* Ag32 = Av + (size_t)(mt * 128 + arow) * K + ahalf * 16;

  f32x4  ar[3][4];
  bf16x8 br[3][2];
  f32x4  acc[4][4] = {};

  auto loadStage = [&](int s, int slot) {
    const float* sp = Ag32 + s * 32;
    ar[slot][0] = *(const f32x4*)(sp);
    ar[slot][1] = *(const f32x4*)(sp + 4);
    ar[slot][2] = *(const f32x4*)(sp + 8);
    ar[slot][3] = *(const f32x4*)(sp + 12);
    const unsigned short* bp = Bpanel + (size_t)s * 512 * 8;
    br[slot][0] = *(const bf16x8*)(bp + (size_t)tid * 8);
    br[slot][1] = *(const bf16x8*)(bp + (size_t)(tid + 256) * 8);
  };
  auto writeStage = [&](int s, int slot) {
    f32x4* r = ar[slot];
    bf16x8 g0, g1;
    g0[0]=(__bf16)r[0][0]; g0[1]=(__bf16)r[0][1]; g0[2]=(__bf16)r[0][2]; g0[3]=(__bf16)r[0][3];
    g0[4]=(__bf16)r[1][0]; g0[5]=(__bf16)r[1][1]; g0[6]=(__bf16)r[1][2]; g0[7]=(__bf16)r[1][3];
    g1[0]=(__bf16)r[2][0]; g1[1]=(__bf16)r[2][1]; g1[2]=(__bf16)r[2][2]; g1[3]=(__bf16)r[2][3];
    g1[4]=(__bf16)r[3][0]; g1[5]=(__bf16)r[3][1]; g1[6]=(__bf16)r[3][2]; g1[7]=(__bf16)r[3][3];
    char* Ad = As + (s & 1) * 8192;
    int u0 = ahalf * 2;
    *(bf16x8*)(Ad + (((u0    ) * 128 + arow) << 4)) = g0;
    *(bf16x8*)(Ad + (((u0 + 1) * 128 + arow) << 4)) = g1;
    char* Bd = Bs + (s & 1) * 8192;
    *(bf16x8*)(Bd + (size_t)tid * 16) = br[slot][0];
    *(bf16x8*)(Bd + (size_t)(tid + 256) * 16) = br[slot][1];
  };
  auto compute = [&](int t) {
    const char* Ad = As + (t & 1) * 8192;
    const char* Bd = Bs + (t & 1) * 8192;
    bf16x8 af[4], bq[4];
#pragma unroll
    for (int mi = 0; mi < 4; mi++) {
      int row = wm * 64 + mi * 16 + r16;
      af[mi] = *(const bf16x8*)(Ad + ((kg * 128 + row) << 4));
    }
#pragma unroll
    for (int ni = 0; ni < 4; ni++) {
      int row = wn * 64 + ni * 16 + r16;
      bq[ni] = *(const bf16x8*)(Bd + ((kg * 128 + row) << 4));
    }
    // swapped operands: thread owns 1 row x 4 consecutive cols
#pragma unroll
    for (int mi = 0; mi < 4; mi++)
#pragma unroll
      for (int ni = 0; ni < 4; ni++)
        acc[mi][ni] = __builtin_amdgcn_mfma_f32_16x16x32_bf16(bq[ni], af[mi], acc[mi][ni], 0, 0, 0);
  };

  // prologue: fill depth-3 pipe, publish stage 0
  loadStage(0, 0); loadStage(1, 1); loadStage(2, 2);
  writeStage(0, 0);
  pipe_barrier();

  auto step = [&](auto TC) {
    constexpr int t = decltype(TC)::v;
    if constexpr (t + 3 < NT) loadStage(t + 3, (t + 3) % 3);
    compute(t);
    if constexpr (t + 1 < NT) {
      writeStage(t + 1, (t + 1) % 3);   // dep-wait: loads issued 2 iters ago
      pipe_barrier();
    }
  };
  step(IC<0>{}); step(IC<1>{}); step(IC<2>{}); step(IC<3>{});
  step(IC<4>{}); step(IC<5>{}); step(IC<6>{}); step(IC<7>{});

  int rowBase = mt * 128 + wm * 64;
  int colBase = nt * 128 + wn * 64;
#pragma unroll
  for (int ni = 0; ni < 4; ni++) {
    int col = colBase + ni * 16 + kg * 4;
    f32x4 bs = *(const f32x4*)(bias + col);
#pragma unroll
    for (int mi = 0; mi < 4; mi++) {
      int row = rowBase + mi * 16 + r16;
      f32x4 v = acc[mi][ni] + bs;
      if (isVal) {
        uint2 st;
        st.x = f2bf(v[0]) | ((unsigned)f2bf(v[1]) << 16);
        st.y = f2bf(v[2]) | ((unsigned)f2bf(v[3]) << 16);
        *(uint2*)(Cval + (size_t)row * 256 + col) = st;
      } else {
        *(f32x4*)(Coff + (size_t)row * 384 + col) = v;
      }
    }
  }
}

// ---------------- final GEMM (gemm3, bf16 staged A): out = interS @ WoS + bout --
__global__ __launch_bounds__(256) void gemm3b_k(const unsigned short* __restrict__ Av,
                                                const unsigned short* __restrict__ WS,
                                                const float* __restrict__ bias,
                                                float* __restrict__ C, int M, int N) {
  constexpr int NT = 8;
  constexpr int STEADY = 4;
  __shared__ char lds[6 * 8192];
  char* As = lds;
  char* Bs = lds + 3 * 8192;

  int tid = threadIdx.x, wave = tid >> 6, lane = tid & 63;
  int ntiles = N >> 7;
  int mt = blockIdx.x / ntiles, nt = blockIdx.x - (blockIdx.x / ntiles) * ntiles;
  int r16 = lane & 15, kg = lane >> 4;
  int wm = wave >> 1, wn = wave & 1;

  const unsigned short* Bpanel = WS + (size_t)nt * (NT * 512 * 8);
  const unsigned short* Apanel = Av + (size_t)mt * (NT * 512 * 8);

  f32x4 acc[4][4] = {};

  auto stageB = [&](int s) {
    char* Bd = Bs + (s % 3) * 8192;
    const unsigned short* sp = Bpanel + (size_t)s * 512 * 8;
#pragma unroll
    for (int j = 0; j < 2; j++) {
      int f = (j * 4 + wave) * 64 + lane;
      gload16(sp + f * 8, Bd + f * 16);
    }
  };
  auto stageA16 = [&](int s) {
    char* Ad = As + (s % 3) * 8192;
    const unsigned short* sp = Apanel + (size_t)s * 512 * 8;
#pragma unroll
    for (int j = 0; j < 2; j++) {
      int f = (j * 4 + wave) * 64 + lane;
      gload16(sp + f * 8, Ad + f * 16);
    }
  };
  auto compute = [&](int s) {
    const char* Ad = As + (s % 3) * 8192;
    const char* Bd = Bs + (s % 3) * 8192;
    bf16x8 af[4], bq[4];
#pragma unroll
    for (int mi = 0; mi < 4; mi++) {
      int row = wm * 64 + mi * 16 + r16;
      af[mi] = *(const bf16x8*)(Ad + ((kg * 128 + row) << 4));
    }
#pragma unroll
    for (int ni = 0; ni < 4; ni++) {
      int row = wn * 64 + ni * 16 + r16;
      bq[ni] = *(const bf16x8*)(Bd + ((kg * 128 + row) << 4));
    }
#pragma unroll
    for (int mi = 0; mi < 4; mi++)
#pragma unroll
      for (int ni = 0; ni < 4; ni++)
        acc[mi][ni] = __builtin_amdgcn_mfma_f32_16x16x32_bf16(bq[ni], af[mi], acc[mi][ni], 0, 0, 0);
  };

  stageA16(0); stageB(0); stageA16(1); stageB(1);
  asm volatile("s_waitcnt vmcnt(%0)" :: "i"(STEADY) : "memory");
  pipe_barrier();

  auto step = [&](auto TC) {
    constexpr int t = decltype(TC)::v;
    if constexpr (t + 2 < NT) { stageA16(t + 2); stageB(t + 2); }
    compute(t);
    if constexpr (t + 1 < NT) {
      if constexpr (t + 2 < NT)
        asm volatile("s_waitcnt vmcnt(%0)" :: "i"(STEADY) : "memory");
      else
        asm volatile("s_waitcnt vmcnt(0)" ::: "memory");
      pipe_barrier();
    }
  };
  step(IC<0>{}); step(IC<1>{}); step(IC<2>{}); step(IC<3>{});
  step(IC<4>{}); step(IC<5>{}); step(IC<6>{}); step(IC<7>{});

  int rowBase = mt * 128 + wm * 64;
  int colBase = nt * 128 + wn * 64;
#pragma unroll
  for (int ni = 0; ni < 4; ni++) {
    int col = colBase + ni * 16 + kg * 4;
    f32x4 bs = *(const f32x4*)(bias + col);
#pragma unroll
    for (int mi = 0; mi < 4; mi++) {
      int row = rowBase + mi * 16 + r16;
      f32x4 v = acc[mi][ni] + bs;
      *(f32x4*)(C + (size_t)row * N + col) = v;
    }
  }
}

// ---------------- sampling: batched 16-gather MLP + b-locality XCD swizzle -----
__global__ __launch_bounds__(256, 3) void sample_k(const float* __restrict__ offattn, // [MQ,384]
                                                   const float* __restrict__ refp,    // [B,Q,4,2]
                                                   const unsigned short* __restrict__ value,
                                                   unsigned short* __restrict__ interS) {
  int orig = blockIdx.x;
  int sb = (orig & 7) * 250 + (orig >> 3);   // bijective (2000 % 8 == 0)
  int t  = sb * 256 + threadIdx.x;
  int bq = t >> 5;
  int h  = (t >> 2) & 7;
  int c0 = (t & 3) << 3;
  int b  = bq / QQ;

  const float* base = offattn + (size_t)bq * 384;

  float lg[16];
  const float4* ab4 = (const float4*)(base + 256 + h * 16);
#pragma unroll
  for (int i = 0; i < 4; i++) {
    float4 v = ab4[i];
    lg[4*i] = v.x; lg[4*i+1] = v.y; lg[4*i+2] = v.z; lg[4*i+3] = v.w;
  }
  float m = -1e30f;
#pragma unroll
  for (int i = 0; i < 16; i++) m = fmaxf(m, lg[i]);
  float s = 0.f;
#pragma unroll
  for (int i = 0; i < 16; i++) { lg[i] = __expf(lg[i] - m); s += lg[i]; }
  float inv = 1.0f / s;

  float4 r01 = ((const float4*)(refp + (size_t)bq * 8))[0];
  float4 r23 = ((const float4*)(refp + (size_t)bq * 8))[1];
  float rxs[4] = {r01.x, r01.z, r23.x, r23.z};
  float rys[4] = {r01.y, r01.w, r23.y, r23.w};

  const unsigned short* vb = value + (size_t)b * (LTOTAL * 256) + h * 32 + c0;
  const int startL[4] = {0, 4096, 5120, 5376};

  float acc[8] = {};
#pragma unroll
  for (int lvl = 0; lvl < 4; lvl++) {
    int   Wi = 64 >> lvl;
    float Wf = (float)Wi;
    float px = rxs[lvl] * Wf - 0.5f;
    float py = rys[lvl] * Wf - 0.5f;
    const unsigned short* vl = vb + (size_t)startL[lvl] * 256;

    const float4* ob4 = (const float4*)(base + h * 32 + lvl * 8);
    float4 o01 = ob4[0], o23 = ob4[1];
    float oxs[4] = {o01.x, o01.z, o23.x, o23.z};
    float oys[4] = {o01.y, o01.w, o23.y, o23.w};

    float cw[16];
    int   coff[16];
#pragma unroll
    for (int pt = 0; pt < 4; pt++) {
      float wa = lg[lvl * 4 + pt] * inv;
      float x = px + oxs[pt];
      float y = py + oys[pt];
      float xf = floorf(x), yf = floorf(y);
      float lx = x - xf, ly = y - yf;
      int x0 = (int)xf, y0 = (int)yf;
      float wx[2] = {1.f - lx, lx};
      float wy[2] = {1.f - ly, ly};
#pragma unroll
      for (int cy = 0; cy < 2; cy++) {
        int Y = y0 + cy;
        bool vy = (unsigned)Y < (unsigned)Wi;
        int Yc = min(max(Y, 0), Wi - 1);
#pragma unroll
        for (int cx = 0; cx < 2; cx++) {
          int X = x0 + cx;
          bool vx = (unsigned)X < (unsigned)Wi;
          int Xc = min(max(X, 0), Wi - 1);
          int c = pt * 4 + cy * 2 + cx;
          cw[c]   = (vx && vy) ? wa * wy[cy] * wx[cx] : 0.f;
          coff[c] = (Yc * Wi + Xc) * 256;
        }
      }
    }
    uint4 raw[16];
#pragma unroll
    for (int c = 0; c < 16; c++) raw[c] = *(const uint4*)(vl + coff[c]);
#pragma unroll
    for (int c = 0; c < 16; c++) {
      float w = cw[c];
      acc[0] += w * b2f_lo(raw[c].x); acc[1] += w * b2f_hi(raw[c].x);
      acc[2] += w * b2f_lo(raw[c].y); acc[3] += w * b2f_hi(raw[c].y);
      acc[4] += w * b2f_lo(raw[c].z); acc[5] += w * b2f_hi(raw[c].z);
      acc[6] += w * b2f_lo(raw[c].w); acc[7] += w * b2f_hi(raw[c].w);
    }
  }

  unsigned o0 = f2bf(acc[0]) | ((unsigned)f2bf(acc[1]) << 16);
  unsigned o1 = f2bf(acc[2]) | ((unsigned)f2bf(acc[3]) << 16);
  unsigned o2 = f2bf(acc[4]) | ((unsigned)f2bf(acc[5]) << 16);
  unsigned o3 = f2bf(acc[6]) | ((unsigned)f2bf(acc[7]) << 16);
  uint4 st = {o0, o1, o2, o3};

  // staged layout: tile = bq>>7, row = bq&127, stage = h, u = c0>>3
  int mtile = bq >> 7, row = bq & 127;
  size_t goff = (((size_t)(mtile * 8 + h)) * 512 + (c0 >> 3) * 128 + row) * 8;
  *(uint4*)(interS + goff) = st;
}

extern "C" void kernel_launch(void* const* d_in, const int* in_sizes, int n_in,
                              void* d_out, int out_size, void* d_ws, size_t ws_size,
                              hipStream_t stream) {
  const float* query  = (const float*)d_in[0];
  const float* refp   = (const float*)d_in[1];
  const float* inputf = (const float*)d_in[2];
  const float* Wv   = (const float*)d_in[5];
  const float* bv   = (const float*)d_in[6];
  const float* Wo   = (const float*)d_in[7];
  const float* bo   = (const float*)d_in[8];
  const float* Wa   = (const float*)d_in[9];
  const float* ba   = (const float*)d_in[10];
  const float* Wout = (const float*)d_in[11];
  const float* bout = (const float*)d_in[12];

  char* p = (char*)d_ws;
  auto alloc = [&](size_t bytes) -> char* {
    char* r = p;
    p += (bytes + 255) & ~(size_t)255;
    return r;
  };
  unsigned short* val   = (unsigned short*)alloc((size_t)MV * 256 * 2);
  unsigned short* WvS   = (unsigned short*)alloc(2 * 4096 * 8 * 2);
  unsigned short* WcS   = (unsigned short*)alloc(3 * 4096 * 8 * 2);
  unsigned short* WoS   = (unsigned short*)alloc(2 * 4096 * 8 * 2);
  float*          bcat  = (float*)alloc(384 * 4);
  float*          offattn = (float*)alloc((size_t)MQ * 384 * 4);
  unsigned short* interS = (unsigned short*)alloc((size_t)MQ * 256 * 2);

  prep_k<<<114, 256, 0, stream>>>(Wv, Wo, Wa, Wout, bo, ba, WvS, WcS, WoS, bcat);

  // fused: value GEMM (1360 blocks) + offattn GEMM (375 blocks), one dispatch
  gemmf_k<<<NVBLK + NOBLK, 256, 0, stream>>>(inputf, query, WvS, WcS, bv, bcat,
                                             val, offattn);
  // sampling -> interS (staged bf16), b-locality XCD swizzle
  sample_k<<<MQ * 32 / 256, 256, 0, stream>>>(offattn, refp, val, interS);
  // out = interS @ Wout + bout -> fp32 d_out
  gemm3b_k<<<(MQ / 128) * 2, 256, 0, stream>>>(interS, WoS, bout, (float*)d_out,
                                               MQ, 256);
}

// Round 14
// 94.068 us; speedup vs baseline: 1.0796x; 1.0796x over previous
//
#include <hip/hip_runtime.h>

#define BB 16
#define QQ 1000
#define NH 8
#define LTOTAL 5440
#define MQ (BB*QQ)      // 16000
#define MV (BB*LTOTAL)  // 87040

typedef __bf16 bf16x8 __attribute__((ext_vector_type(8)));
typedef float  f32x4  __attribute__((ext_vector_type(4)));

template <int N> struct IC { static constexpr int v = N; };

__device__ __forceinline__ unsigned short f2bf(float f) {
  unsigned u = __builtin_bit_cast(unsigned, f);
  u += 0x7fffu + ((u >> 16) & 1u);
  return (unsigned short)(u >> 16);
}
__device__ __forceinline__ float b2f_lo(unsigned u) {
  return __builtin_bit_cast(float, u << 16);
}
__device__ __forceinline__ float b2f_hi(unsigned u) {
  return __builtin_bit_cast(float, u & 0xffff0000u);
}

__device__ __forceinline__ void gload16(const void* g, void* l) {
  __builtin_amdgcn_global_load_lds(
      (const __attribute__((address_space(1))) unsigned int*)g,
      (__attribute__((address_space(3))) unsigned int*)l, 16, 0, 0);
}

// lgkmcnt(0) + raw barrier; vmcnt deliberately NOT drained.
__device__ __forceinline__ void pipe_barrier() {
  asm volatile("s_waitcnt lgkmcnt(0)" ::: "memory");
  __builtin_amdgcn_sched_barrier(0);
  __builtin_amdgcn_s_barrier();
  __builtin_amdgcn_sched_barrier(0);
}

// ---------------- prep: weights -> [panel][k_octet][n] granule layout + biases --
__global__ __launch_bounds__(256) void prep_k(const float* __restrict__ Wv,
                                              const float* __restrict__ Wo,
                                              const float* __restrict__ Wa,
                                              const float* __restrict__ Wout,
                                              const float* __restrict__ bo,
                                              const float* __restrict__ ba,
                                              unsigned short* __restrict__ WvS,  // 2 panels
                                              unsigned short* __restrict__ WcS,  // 3 panels
                                              unsigned short* __restrict__ WoS,  // 2 panels
                                              float* __restrict__ bcat) {
  int i = blockIdx.x * 256 + threadIdx.x;
  if (i < 28672) {
    const float* src;
    unsigned short* dst;
    int g, srcN;
    if (i < 8192)       { g = i;         dst = WvS; src = Wv;   srcN = 256; }
    else if (i < 20480) { g = i - 8192;  dst = WcS; src = Wo;   srcN = 256; }
    else                { g = i - 20480; dst = WoS; src = Wout; srcN = 256; }
    int panel = g >> 12, ko = (g >> 7) & 31, row = g & 127;
    int kbase = ko * 8;
    int n = panel * 128 + row;
    if (dst == WcS && panel == 2) { src = Wa; srcN = 128; n = row; }
    bf16x8 r;
#pragma unroll
    for (int e = 0; e < 8; e++) r[e] = (__bf16)src[(size_t)(kbase + e) * srcN + n];
    *(bf16x8*)(dst + (size_t)g * 8) = r;
  } else if (i < 29056) {
    int j = i - 28672;
    bcat[j] = j < 256 ? bo[j] : ba[j - 256];
  }
}

// ---------------- value GEMM: 128x256 tile (A read ONCE), 512 thr / 8 waves ----
// val = input_flatten @ WvS^T + bv -> bf16 [MV,256]. Schedule = R11 depth-2:
// reg-staged fp32 A (2 slots), in-loop B LDS-DMA with THREE B stages (R13 bug:
// 2 stages raced with depth-2 prefetch — stageB(t+2) wrote the buffer
// compute(t) was reading). counted vmcnt(4), raw barriers, XCD swizzle.
__global__ __launch_bounds__(512) void gemmv_k(const float* __restrict__ Av,
                                               const unsigned short* __restrict__ WvS,
                                               const float* __restrict__ bias,
                                               unsigned short* __restrict__ C) {
  constexpr int K = 256, NT = 8;
  __shared__ char lds[2 * 8192 + 3 * 16384];   // A 2 stages + B 3 stages = 64KB
  char* As = lds;
  char* Bs = lds + 16384;

  int orig = blockIdx.x;
  int mt = (orig & 7) * 85 + (orig >> 3);      // bijective: 680 = 8*85

  int tid = threadIdx.x, wave = tid >> 6, lane = tid & 63;
  int r16 = lane & 15, kg = lane >> 4;
  int wm = wave >> 2, wn = wave & 3;           // 2m x 4n of 64x64
  int arow = tid >> 2, au = tid & 3;           // A: row 0..127, k-octet 0..3

  const float* Ag32 = Av + (size_t)(mt * 128 + arow) * K + au * 8;

  f32x4 ar[2][2];
  f32x4 acc[4][4] = {};

  auto loadA = [&](int s, int slot) {
    const float* sp = Ag32 + s * 32;
    ar[slot][0] = *(const f32x4*)(sp);
    ar[slot][1] = *(const f32x4*)(sp + 4);
  };
  auto writeA = [&](int s, int slot) {
    f32x4 lo = ar[slot][0], hi = ar[slot][1];
    bf16x8 g;
    g[0]=(__bf16)lo[0]; g[1]=(__bf16)lo[1]; g[2]=(__bf16)lo[2]; g[3]=(__bf16)lo[3];
    g[4]=(__bf16)hi[0]; g[5]=(__bf16)hi[1]; g[6]=(__bf16)hi[2]; g[7]=(__bf16)hi[3];
    char* Ad = As + (s & 1) * 8192;
    *(bf16x8*)(Ad + ((au * 128 + arow) << 4)) = g;
  };
  auto stageB = [&](int s) {
    char* Bd = Bs + (s % 3) * 16384;
#pragma unroll
    for (int j = 0; j < 2; j++) {
      int f = j * 512 + tid;                   // 1024 granules: u*256 + col
      int u = f >> 8, col = f & 255;
      const unsigned short* sp = WvS +
          ((size_t)(col >> 7) * 4096 + (size_t)(s * 4 + u) * 128 + (col & 127)) * 8;
      gload16(sp, Bd + (size_t)f * 16);
    }
  };
  auto compute = [&](int t) {
    const char* Ad = As + (t & 1) * 8192;
    const char* Bd = Bs + (t % 3) * 16384;
    bf16x8 af[4], bq[4];
#pragma unroll
    for (int mi = 0; mi < 4; mi++) {
      int row = wm * 64 + mi * 16 + r16;
      af[mi] = *(const bf16x8*)(Ad + ((kg * 128 + row) << 4));
    }
#pragma unroll
    for (int ni = 0; ni < 4; ni++) {
      int col = wn * 64 + ni * 16 + r16;
      bq[ni] = *(const bf16x8*)(Bd + ((kg * 256 + col) << 4));
    }
#pragma unroll
    for (int mi = 0; mi < 4; mi++)
#pragma unroll
      for (int ni = 0; ni < 4; ni++)
        acc[mi][ni] = __builtin_amdgcn_mfma_f32_16x16x32_bf16(bq[ni], af[mi], acc[mi][ni], 0, 0, 0);
  };

  loadA(0, 0); stageB(0); loadA(1, 1); stageB(1);
  writeA(0, 0);
  asm volatile("s_waitcnt vmcnt(4)" ::: "memory");
  pipe_barrier();

  auto step = [&](auto TC) {
    constexpr int t = decltype(TC)::v;
    if constexpr (t + 2 < NT) {
      loadA(t + 2, t & 1);
      stageB(t + 2);
    }
    compute(t);
    if constexpr (t + 1 < NT) {
      writeA(t + 1, (t + 1) & 1);              // dep-waits overlap B vmcnt wait
      if constexpr (t + 2 < NT)
        asm volatile("s_waitcnt vmcnt(4)" ::: "memory");
      else
        asm volatile("s_waitcnt vmcnt(0)" ::: "memory");
      pipe_barrier();
    }
  };
  step(IC<0>{}); step(IC<1>{}); step(IC<2>{}); step(IC<3>{});
  step(IC<4>{}); step(IC<5>{}); step(IC<6>{}); step(IC<7>{});

  int rowBase = mt * 128 + wm * 64;
  int colBase = wn * 64;
#pragma unroll
  for (int ni = 0; ni < 4; ni++) {
    int col = colBase + ni * 16 + kg * 4;
    f32x4 bs = *(const f32x4*)(bias + col);
#pragma unroll
    for (int mi = 0; mi < 4; mi++) {
      int row = rowBase + mi * 16 + r16;
      f32x4 v = acc[mi][ni] + bs;
      uint2 st;
      st.x = f2bf(v[0]) | ((unsigned)f2bf(v[1]) << 16);
      st.y = f2bf(v[2]) | ((unsigned)f2bf(v[3]) << 16);
      *(uint2*)(C + (size_t)row * 256 + col) = st;
    }
  }
}

// ---------------- offattn GEMM (R11 gemmf offattn path, standalone) ------------
__global__ __launch_bounds__(256) void gemmo_k(const float* __restrict__ Av,
                                               const unsigned short* __restrict__ WcS,
                                               const float* __restrict__ bias,
                                               float* __restrict__ Coff) {
  constexpr int K = 256, NT = 8;
  constexpr int NWG = (MQ / 128) * 3;          // 375
  constexpr int QC = NWG / 8, RC = NWG % 8;    // 46, 7
  __shared__ char lds[5 * 8192];
  char* As = lds;
  char* Bs = lds + 2 * 8192;

  int orig = blockIdx.x;
  int xcd = orig & 7, pos = orig >> 3;
  int bid = (xcd < RC ? xcd * (QC + 1) : RC * (QC + 1) + (xcd - RC) * QC) + pos;

  int tid = threadIdx.x, wave = tid >> 6, lane = tid & 63;
  int mt = bid / 3, nt = bid - mt * 3;
  int r16 = lane & 15, kg = lane >> 4;
  int wm = wave >> 1, wn = wave & 1;
  int arow = tid >> 1, ahalf = tid & 1;

  const unsigned short* Bpanel = WcS + (size_t)nt * (NT * 512 * 8);
  const float* Ag32 = Av + (size_t)(mt * 128 + arow) * K + ahalf * 16;

  f32x4 ar[2][4];
  f32x4 acc[4][4] = {};

  auto stageB = [&](int s) {
    char* Bd = Bs + (s % 3) * 8192;
    const unsigned short* sp = Bpanel + (size_t)s * 512 * 8;
#pragma unroll
    for (int j = 0; j < 2; j++) {
      int f = (j * 4 + wave) * 64 + lane;
      gload16(sp + f * 8, Bd + f * 16);
    }
  };
  auto loadA32 = [&](int s, f32x4* r) {
    const float* sp = Ag32 + s * 32;
    r[0] = *(const f32x4*)(sp);
    r[1] = *(const f32x4*)(sp + 4);
    r[2] = *(const f32x4*)(sp + 8);
    r[3] = *(const f32x4*)(sp + 12);
  };
  auto writeA32 = [&](int slot, f32x4* r) {
    bf16x8 g0, g1;
    g0[0]=(__bf16)r[0][0]; g0[1]=(__bf16)r[0][1]; g0[2]=(__bf16)r[0][2]; g0[3]=(__bf16)r[0][3];
    g0[4]=(__bf16)r[1][0]; g0[5]=(__bf16)r[1][1]; g0[6]=(__bf16)r[1][2]; g0[7]=(__bf16)r[1][3];
    g1[0]=(__bf16)r[2][0]; g1[1]=(__bf16)r[2][1]; g1[2]=(__bf16)r[2][2]; g1[3]=(__bf16)r[2][3];
    g1[4]=(__bf16)r[3][0]; g1[5]=(__bf16)r[3][1]; g1[6]=(__bf16)r[3][2]; g1[7]=(__bf16)r[3][3];
    char* Ad = As + slot * 8192;
    int u0 = ahalf * 2;
    *(bf16x8*)(Ad + (((u0    ) * 128 + arow) << 4)) = g0;
    *(bf16x8*)(Ad + (((u0 + 1) * 128 + arow) << 4)) = g1;
  };
  auto compute = [&](int sa, int sb) {
    const char* Ad = As + sa * 8192;
    const char* Bd = Bs + sb * 8192;
    bf16x8 af[4], bq[4];
#pragma unroll
    for (int mi = 0; mi < 4; mi++) {
      int row = wm * 64 + mi * 16 + r16;
      af[mi] = *(const bf16x8*)(Ad + ((kg * 128 + row) << 4));
    }
#pragma unroll
    for (int ni = 0; ni < 4; ni++) {
      int row = wn * 64 + ni * 16 + r16;
      bq[ni] = *(const bf16x8*)(Bd + ((kg * 128 + row) << 4));
    }
#pragma unroll
    for (int mi = 0; mi < 4; mi++)
#pragma unroll
      for (int ni = 0; ni < 4; ni++)
        acc[mi][ni] = __builtin_amdgcn_mfma_f32_16x16x32_bf16(bq[ni], af[mi], acc[mi][ni], 0, 0, 0);
  };

  loadA32(0, ar[0]); stageB(0); loadA32(1, ar[1]); stageB(1);
  writeA32(0, ar[0]);
  asm volatile("s_waitcnt vmcnt(6)" ::: "memory");
  pipe_barrier();

  auto step = [&](auto TC) {
    constexpr int t = decltype(TC)::v;
    if constexpr (t + 2 < NT) {
      loadA32(t + 2, ar[(t + 2) & 1]);
      stageB(t + 2);
    }
    compute(t & 1, t % 3);
    if constexpr (t + 1 < NT) {
      writeA32((t + 1) & 1, ar[(t + 1) & 1]);
      if constexpr (t + 2 < NT)
        asm volatile("s_waitcnt vmcnt(6)" ::: "memory");
      else
        asm volatile("s_waitcnt vmcnt(0)" ::: "memory");
      pipe_barrier();
    }
  };
  step(IC<0>{}); step(IC<1>{}); step(IC<2>{}); step(IC<3>{});
  step(IC<4>{}); step(IC<5>{}); step(IC<6>{}); step(IC<7>{});

  int rowBase = mt * 128 + wm * 64;
  int colBase = nt * 128 + wn * 64;
#pragma unroll
  for (int ni = 0; ni < 4; ni++) {
    int col = colBase + ni * 16 + kg * 4;
    f32x4 bs = *(const f32x4*)(bias + col);
#pragma unroll
    for (int mi = 0; mi < 4; mi++) {
      int row = rowBase + mi * 16 + r16;
      f32x4 v = acc[mi][ni] + bs;
      *(f32x4*)(Coff + (size_t)row * 384 + col) = v;
    }
  }
}

// ---------------- final GEMM (R11 verbatim) ------------------------------------
__global__ __launch_bounds__(256) void gemm3b_k(const unsigned short* __restrict__ Av,
                                                const unsigned short* __restrict__ WS,
                                                const float* __restrict__ bias,
                                                float* __restrict__ C, int M, int N) {
  constexpr int NT = 8;
  constexpr int STEADY = 4;
  __shared__ char lds[6 * 8192];
  char* As = lds;
  char* Bs = lds + 3 * 8192;

  int tid = threadIdx.x, wave = tid >> 6, lane = tid & 63;
  int ntiles = N >> 7;
  int mt = blockIdx.x / ntiles, nt = blockIdx.x - (blockIdx.x / ntiles) * ntiles;
  int r16 = lane & 15, kg = lane >> 4;
  int wm = wave >> 1, wn = wave & 1;

  const unsigned short* Bpanel = WS + (size_t)nt * (NT * 512 * 8);
  const unsigned short* Apanel = Av + (size_t)mt * (NT * 512 * 8);

  f32x4 acc[4][4] = {};

  auto stageB = [&](int s) {
    char* Bd = Bs + (s % 3) * 8192;
    const unsigned short* sp = Bpanel + (size_t)s * 512 * 8;
#pragma unroll
    for (int j = 0; j < 2; j++) {
      int f = (j * 4 + wave) * 64 + lane;
      gload16(sp + f * 8, Bd + f * 16);
    }
  };
  auto stageA16 = [&](int s) {
    char* Ad = As + (s % 3) * 8192;
    const unsigned short* sp = Apanel + (size_t)s * 512 * 8;
#pragma unroll
    for (int j = 0; j < 2; j++) {
      int f = (j * 4 + wave) * 64 + lane;
      gload16(sp + f * 8, Ad + f * 16);
    }
  };
  auto compute = [&](int s) {
    const char* Ad = As + (s % 3) * 8192;
    const char* Bd = Bs + (s % 3) * 8192;
    bf16x8 af[4], bq[4];
#pragma unroll
    for (int mi = 0; mi < 4; mi++) {
      int row = wm * 64 + mi * 16 + r16;
      af[mi] = *(const bf16x8*)(Ad + ((kg * 128 + row) << 4));
    }
#pragma unroll
    for (int ni = 0; ni < 4; ni++) {
      int row = wn * 64 + ni * 16 + r16;
      bq[ni] = *(const bf16x8*)(Bd + ((kg * 128 + row) << 4));
    }
#pragma unroll
    for (int mi = 0; mi < 4; mi++)
#pragma unroll
      for (int ni = 0; ni < 4; ni++)
        acc[mi][ni] = __builtin_amdgcn_mfma_f32_16x16x32_bf16(bq[ni], af[mi], acc[mi][ni], 0, 0, 0);
  };

  stageA16(0); stageB(0); stageA16(1); stageB(1);
  asm volatile("s_waitcnt vmcnt(%0)" :: "i"(STEADY) : "memory");
  pipe_barrier();

  auto step = [&](auto TC) {
    constexpr int t = decltype(TC)::v;
    if constexpr (t + 2 < NT) { stageA16(t + 2); stageB(t + 2); }
    compute(t);
    if constexpr (t + 1 < NT) {
      if constexpr (t + 2 < NT)
        asm volatile("s_waitcnt vmcnt(%0)" :: "i"(STEADY) : "memory");
      else
        asm volatile("s_waitcnt vmcnt(0)" ::: "memory");
      pipe_barrier();
    }
  };
  step(IC<0>{}); step(IC<1>{}); step(IC<2>{}); step(IC<3>{});
  step(IC<4>{}); step(IC<5>{}); step(IC<6>{}); step(IC<7>{});

  int rowBase = mt * 128 + wm * 64;
  int colBase = nt * 128 + wn * 64;
#pragma unroll
  for (int ni = 0; ni < 4; ni++) {
    int col = colBase + ni * 16 + kg * 4;
    f32x4 bs = *(const f32x4*)(bias + col);
#pragma unroll
    for (int mi = 0; mi < 4; mi++) {
      int row = rowBase + mi * 16 + r16;
      f32x4 v = acc[mi][ni] + bs;
      *(f32x4*)(C + (size_t)row * N + col) = v;
    }
  }
}

// ---------------- sampling (R11 verbatim): 16-gather MLP + b-locality swizzle --
__global__ __launch_bounds__(256, 3) void sample_k(const float* __restrict__ offattn, // [MQ,384]
                                                   const float* __restrict__ refp,    // [B,Q,4,2]
                                                   const unsigned short* __restrict__ value,
                                                   unsigned short* __restrict__ interS) {
  int orig = blockIdx.x;
  int sb = (orig & 7) * 250 + (orig >> 3);   // bijective (2000 % 8 == 0)
  int t  = sb * 256 + threadIdx.x;
  int bq = t >> 5;
  int h  = (t >> 2) & 7;
  int c0 = (t & 3) << 3;
  int b  = bq / QQ;

  const float* base = offattn + (size_t)bq * 384;

  float lg[16];
  const float4* ab4 = (const float4*)(base + 256 + h * 16);
#pragma unroll
  for (int i = 0; i < 4; i++) {
    float4 v = ab4[i];
    lg[4*i] = v.x; lg[4*i+1] = v.y; lg[4*i+2] = v.z; lg[4*i+3] = v.w;
  }
  float m = -1e30f;
#pragma unroll
  for (int i = 0; i < 16; i++) m = fmaxf(m, lg[i]);
  float s = 0.f;
#pragma unroll
  for (int i = 0; i < 16; i++) { lg[i] = __expf(lg[i] - m); s += lg[i]; }
  float inv = 1.0f / s;

  float4 r01 = ((const float4*)(refp + (size_t)bq * 8))[0];
  float4 r23 = ((const float4*)(refp + (size_t)bq * 8))[1];
  float rxs[4] = {r01.x, r01.z, r23.x, r23.z};
  float rys[4] = {r01.y, r01.w, r23.y, r23.w};

  const unsigned short* vb = value + (size_t)b * (LTOTAL * 256) + h * 32 + c0;
  const int startL[4] = {0, 4096, 5120, 5376};

  float acc[8] = {};
#pragma unroll
  for (int lvl = 0; lvl < 4; lvl++) {
    int   Wi = 64 >> lvl;
    float Wf = (float)Wi;
    float px = rxs[lvl] * Wf - 0.5f;
    float py = rys[lvl] * Wf - 0.5f;
    const unsigned short* vl = vb + (size_t)startL[lvl] * 256;

    const float4* ob4 = (const float4*)(base + h * 32 + lvl * 8);
    float4 o01 = ob4[0], o23 = ob4[1];
    float oxs[4] = {o01.x, o01.z, o23.x, o23.z};
    float oys[4] = {o01.y, o01.w, o23.y, o23.w};

    float cw[16];
    int   coff[16];
#pragma unroll
    for (int pt = 0; pt < 4; pt++) {
      float wa = lg[lvl * 4 + pt] * inv;
      float x = px + oxs[pt];
      float y = py + oys[pt];
      float xf = floorf(x), yf = floorf(y);
      float lx = x - xf, ly = y - yf;
      int x0 = (int)xf, y0 = (int)yf;
      float wx[2] = {1.f - lx, lx};
      float wy[2] = {1.f - ly, ly};
#pragma unroll
      for (int cy = 0; cy < 2; cy++) {
        int Y = y0 + cy;
        bool vy = (unsigned)Y < (unsigned)Wi;
        int Yc = min(max(Y, 0), Wi - 1);
#pragma unroll
        for (int cx = 0; cx < 2; cx++) {
          int X = x0 + cx;
          bool vx = (unsigned)X < (unsigned)Wi;
          int Xc = min(max(X, 0), Wi - 1);
          int c = pt * 4 + cy * 2 + cx;
          cw[c]   = (vx && vy) ? wa * wy[cy] * wx[cx] : 0.f;
          coff[c] = (Yc * Wi + Xc) * 256;
        }
      }
    }
    uint4 raw[16];
#pragma unroll
    for (int c = 0; c < 16; c++) raw[c] = *(const uint4*)(vl + coff[c]);
#pragma unroll
    for (int c = 0; c < 16; c++) {
      float w = cw[c];
      acc[0] += w * b2f_lo(raw[c].x); acc[1] += w * b2f_hi(raw[c].x);
      acc[2] += w * b2f_lo(raw[c].y); acc[3] += w * b2f_hi(raw[c].y);
      acc[4] += w * b2f_lo(raw[c].z); acc[5] += w * b2f_hi(raw[c].z);
      acc[6] += w * b2f_lo(raw[c].w); acc[7] += w * b2f_hi(raw[c].w);
    }
  }

  unsigned o0 = f2bf(acc[0]) | ((unsigned)f2bf(acc[1]) << 16);
  unsigned o1 = f2bf(acc[2]) | ((unsigned)f2bf(acc[3]) << 16);
  unsigned o2 = f2bf(acc[4]) | ((unsigned)f2bf(acc[5]) << 16);
  unsigned o3 = f2bf(acc[6]) | ((unsigned)f2bf(acc[7]) << 16);
  uint4 st = {o0, o1, o2, o3};

  // staged layout: tile = bq>>7, row = bq&127, stage = h, u = c0>>3
  int mtile = bq >> 7, row = bq & 127;
  size_t goff = (((size_t)(mtile * 8 + h)) * 512 + (c0 >> 3) * 128 + row) * 8;
  *(uint4*)(interS + goff) = st;
}

extern "C" void kernel_launch(void* const* d_in, const int* in_sizes, int n_in,
                              void* d_out, int out_size, void* d_ws, size_t ws_size,
                              hipStream_t stream) {
  const float* query  = (const float*)d_in[0];
  const float* refp   = (const float*)d_in[1];
  const float* inputf = (const float*)d_in[2];
  const float* Wv   = (const float*)d_in[5];
  const float* bv   = (const float*)d_in[6];
  const float* Wo   = (const float*)d_in[7];
  const float* bo   = (const float*)d_in[8];
  const float* Wa   = (const float*)d_in[9];
  const float* ba   = (const float*)d_in[10];
  const float* Wout = (const float*)d_in[11];
  const float* bout = (const float*)d_in[12];

  char* p = (char*)d_ws;
  auto alloc = [&](size_t bytes) -> char* {
    char* r = p;
    p += (bytes + 255) & ~(size_t)255;
    return r;
  };
  unsigned short* val   = (unsigned short*)alloc((size_t)MV * 256 * 2);
  unsigned short* WvS   = (unsigned short*)alloc(2 * 4096 * 8 * 2);
  unsigned short* WcS   = (unsigned short*)alloc(3 * 4096 * 8 * 2);
  unsigned short* WoS   = (unsigned short*)alloc(2 * 4096 * 8 * 2);
  float*          bcat  = (float*)alloc(384 * 4);
  float*          offattn = (float*)alloc((size_t)MQ * 384 * 4);
  unsigned short* interS = (unsigned short*)alloc((size_t)MQ * 256 * 2);

  prep_k<<<114, 256, 0, stream>>>(Wv, Wo, Wa, Wout, bo, ba, WvS, WcS, WoS, bcat);

  // value = input_flatten @ Wv + bv -> bf16 [MV,256]  (128x256 tiles, A once)
  gemmv_k<<<MV / 128, 512, 0, stream>>>(inputf, WvS, bv, val);
  // offattn = query @ [Wo|Wa] + [bo|ba] -> fp32 [MQ,384]
  gemmo_k<<<(MQ / 128) * 3, 256, 0, stream>>>(query, WcS, bcat, offattn);
  // sampling -> interS (staged bf16), b-locality XCD swizzle
  sample_k<<<MQ * 32 / 256, 256, 0, stream>>>(offattn, refp, val, interS);
  // out = interS @ Wout + bout -> fp32 d_out
  gemm3b_k<<<(MQ / 128) * 2, 256, 0, stream>>>(interS, WoS, bout, (float*)d_out,
                                               MQ, 256);
}

// Round 15
// 89.560 us; speedup vs baseline: 1.1339x; 1.0503x over previous
//
#include <hip/hip_runtime.h>

#define BB 16
#define QQ 1000
#define NH 8
#define LTOTAL 5440
#define MQ (BB*QQ)      // 16000
#define MV (BB*LTOTAL)  // 87040
#define NVBLK ((MV/128)*2)   // 1360 value-GEMM blocks
#define NOBLK ((MQ/128)*3)   // 375 offattn-GEMM blocks

typedef __bf16 bf16x8 __attribute__((ext_vector_type(8)));
typedef float  f32x4  __attribute__((ext_vector_type(4)));

template <int N> struct IC { static constexpr int v = N; };

__device__ __forceinline__ unsigned short f2bf(float f) {
  unsigned u = __builtin_bit_cast(unsigned, f);
  u += 0x7fffu + ((u >> 16) & 1u);
  return (unsigned short)(u >> 16);
}
__device__ __forceinline__ float b2f_lo(unsigned u) {
  return __builtin_bit_cast(float, u << 16);
}
__device__ __forceinline__ float b2f_hi(unsigned u) {
  return __builtin_bit_cast(float, u & 0xffff0000u);
}

__device__ __forceinline__ void gload16(const void* g, void* l) {
  __builtin_amdgcn_global_load_lds(
      (const __attribute__((address_space(1))) unsigned int*)g,
      (__attribute__((address_space(3))) unsigned int*)l, 16, 0, 0);
}

// lgkmcnt(0) + raw barrier; vmcnt deliberately NOT drained.
__device__ __forceinline__ void pipe_barrier() {
  asm volatile("s_waitcnt lgkmcnt(0)" ::: "memory");
  __builtin_amdgcn_sched_barrier(0);
  __builtin_amdgcn_s_barrier();
  __builtin_amdgcn_sched_barrier(0);
}

// bijective XCD swizzle for any nwg (m204 formula)
__device__ __forceinline__ int xcd_swz(int orig, int nwg) {
  int q = nwg >> 3, r = nwg & 7;
  int xcd = orig & 7, pos = orig >> 3;
  return (xcd < r ? xcd * (q + 1) : r * (q + 1) + (xcd - r) * q) + pos;
}

// ---------------- prep: weights -> [panel][k_octet][n] granule layout + biases --
__global__ __launch_bounds__(256) void prep_k(const float* __restrict__ Wv,
                                              const float* __restrict__ Wo,
                                              const float* __restrict__ Wa,
                                              const float* __restrict__ Wout,
                                              const float* __restrict__ bo,
                                              const float* __restrict__ ba,
                                              unsigned short* __restrict__ WvS,  // 2 panels
                                              unsigned short* __restrict__ WcS,  // 3 panels
                                              unsigned short* __restrict__ WoS,  // 2 panels
                                              float* __restrict__ bcat) {
  int i = blockIdx.x * 256 + threadIdx.x;
  if (i < 28672) {
    const float* src;
    unsigned short* dst;
    int g, srcN;
    if (i < 8192)       { g = i;         dst = WvS; src = Wv;   srcN = 256; }
    else if (i < 20480) { g = i - 8192;  dst = WcS; src = Wo;   srcN = 256; }
    else                { g = i - 20480; dst = WoS; src = Wout; srcN = 256; }
    int panel = g >> 12, ko = (g >> 7) & 31, row = g & 127;
    int kbase = ko * 8;
    int n = panel * 128 + row;
    if (dst == WcS && panel == 2) { src = Wa; srcN = 128; n = row; }
    bf16x8 r;
#pragma unroll
    for (int e = 0; e < 8; e++) r[e] = (__bf16)src[(size_t)(kbase + e) * srcN + n];
    *(bf16x8*)(dst + (size_t)g * 8) = r;
  } else if (i < 29056) {
    int j = i - 28672;
    bcat[j] = j < 256 ? bo[j] : ba[j - 256];
  }
}

// ---------------- fused value+offattn GEMM (R11 verbatim — best measured) ------
__global__ __launch_bounds__(256) void gemmf_k(const float* __restrict__ Aval,
                                               const float* __restrict__ Aoff,
                                               const unsigned short* __restrict__ WvS,
                                               const unsigned short* __restrict__ WcS,
                                               const float* __restrict__ bv,
                                               const float* __restrict__ bcat,
                                               unsigned short* __restrict__ Cval,
                                               float* __restrict__ Coff) {
  constexpr int K = 256, NT = 8;
  constexpr int STEADY = 6;
  constexpr int NWG = NVBLK + NOBLK;           // 1735
  __shared__ char lds[5 * 8192];               // 2 A stages + 3 B stages
  char* As = lds;
  char* Bs = lds + 2 * 8192;

  int bid = xcd_swz(blockIdx.x, NWG);

  bool isVal = bid < NVBLK;
  int vbid = isVal ? bid : bid - NVBLK;
  int ntiles = isVal ? 2 : 3;
  const float* Av = isVal ? Aval : Aoff;
  const unsigned short* WS = isVal ? WvS : WcS;
  const float* bias = isVal ? bv : bcat;

  int tid = threadIdx.x, wave = tid >> 6, lane = tid & 63;
  int mt = vbid / ntiles, nt = vbid - mt * ntiles;
  int r16 = lane & 15, kg = lane >> 4;
  int wm = wave >> 1, wn = wave & 1;
  int arow = tid >> 1, ahalf = tid & 1;

  const unsigned short* Bpanel = WS + (size_t)nt * (NT * 512 * 8);
  const float* Ag32 = Av + (size_t)(mt * 128 + arow) * K + ahalf * 16;

  f32x4 ar[2][4];
  f32x4 acc[4][4] = {};

  auto stageB = [&](int s) {
    char* Bd = Bs + (s % 3) * 8192;
    const unsigned short* sp = Bpanel + (size_t)s * 512 * 8;
#pragma unroll
    for (int j = 0; j < 2; j++) {
      int f = (j * 4 + wave) * 64 + lane;
      gload16(sp + f * 8, Bd + f * 16);
    }
  };
  auto loadA32 = [&](int s, f32x4* r) {
    const float* sp = Ag32 + s * 32;
    r[0] = *(const f32x4*)(sp);
    r[1] = *(const f32x4*)(sp + 4);
    r[2] = *(const f32x4*)(sp + 8);
    r[3] = *(const f32x4*)(sp + 12);
  };
  auto writeA32 = [&](int slot, f32x4* r) {
    bf16x8 g0, g1;
    g0[0]=(__bf16)r[0][0]; g0[1]=(__bf16)r[0][1]; g0[2]=(__bf16)r[0][2]; g0[3]=(__bf16)r[0][3];
    g0[4]=(__bf16)r[1][0]; g0[5]=(__bf16)r[1][1]; g0[6]=(__bf16)r[1][2]; g0[7]=(__bf16)r[1][3];
    g1[0]=(__bf16)r[2][0]; g1[1]=(__bf16)r[2][1]; g1[2]=(__bf16)r[2][2]; g1[3]=(__bf16)r[2][3];
    g1[4]=(__bf16)r[3][0]; g1[5]=(__bf16)r[3][1]; g1[6]=(__bf16)r[3][2]; g1[7]=(__bf16)r[3][3];
    char* Ad = As + slot * 8192;
    int u0 = ahalf * 2;
    *(bf16x8*)(Ad + (((u0    ) * 128 + arow) << 4)) = g0;
    *(bf16x8*)(Ad + (((u0 + 1) * 128 + arow) << 4)) = g1;
  };
  auto compute = [&](int sa, int sb) {
    const char* Ad = As + sa * 8192;
    const char* Bd = Bs + sb * 8192;
    bf16x8 af[4], bq[4];
#pragma unroll
    for (int mi = 0; mi < 4; mi++) {
      int row = wm * 64 + mi * 16 + r16;
      af[mi] = *(const bf16x8*)(Ad + ((kg * 128 + row) << 4));
    }
#pragma unroll
    for (int ni = 0; ni < 4; ni++) {
      int row = wn * 64 + ni * 16 + r16;
      bq[ni] = *(const bf16x8*)(Bd + ((kg * 128 + row) << 4));
    }
    // swapped operands: thread owns 1 row x 4 consecutive cols
#pragma unroll
    for (int mi = 0; mi < 4; mi++)
#pragma unroll
      for (int ni = 0; ni < 4; ni++)
        acc[mi][ni] = __builtin_amdgcn_mfma_f32_16x16x32_bf16(bq[ni], af[mi], acc[mi][ni], 0, 0, 0);
  };

  loadA32(0, ar[0]); stageB(0); loadA32(1, ar[1]); stageB(1);
  writeA32(0, ar[0]);
  asm volatile("s_waitcnt vmcnt(%0)" :: "i"(STEADY) : "memory");
  pipe_barrier();

  auto step = [&](auto TC) {
    constexpr int t = decltype(TC)::v;
    if constexpr (t + 2 < NT) {
      loadA32(t + 2, ar[(t + 2) & 1]);
      stageB(t + 2);
    }
    compute(t & 1, t % 3);
    if constexpr (t + 1 < NT) {
      writeA32((t + 1) & 1, ar[(t + 1) & 1]);  // dep-waits overlap B vmcnt wait
      if constexpr (t + 2 < NT)
        asm volatile("s_waitcnt vmcnt(%0)" :: "i"(STEADY) : "memory");
      else
        asm volatile("s_waitcnt vmcnt(0)" ::: "memory");
      pipe_barrier();
    }
  };
  step(IC<0>{}); step(IC<1>{}); step(IC<2>{}); step(IC<3>{});
  step(IC<4>{}); step(IC<5>{}); step(IC<6>{}); step(IC<7>{});

  int rowBase = mt * 128 + wm * 64;
  int colBase = nt * 128 + wn * 64;
#pragma unroll
  for (int ni = 0; ni < 4; ni++) {
    int col = colBase + ni * 16 + kg * 4;
    f32x4 bs = *(const f32x4*)(bias + col);
#pragma unroll
    for (int mi = 0; mi < 4; mi++) {
      int row = rowBase + mi * 16 + r16;
      f32x4 v = acc[mi][ni] + bs;
      if (isVal) {
        uint2 st;
        st.x = f2bf(v[0]) | ((unsigned)f2bf(v[1]) << 16);
        st.y = f2bf(v[2]) | ((unsigned)f2bf(v[3]) << 16);
        *(uint2*)(Cval + (size_t)row * 256 + col) = st;
      } else {
        *(f32x4*)(Coff + (size_t)row * 384 + col) = v;
      }
    }
  }
}

// ---------------- final GEMM (R11 + XCD swizzle): out = interS @ WoS + bout ----
__global__ __launch_bounds__(256) void gemm3b_k(const unsigned short* __restrict__ Av,
                                                const unsigned short* __restrict__ WS,
                                                const float* __restrict__ bias,
                                                float* __restrict__ C, int M, int N) {
  constexpr int NT = 8;
  constexpr int STEADY = 4;
  __shared__ char lds[6 * 8192];
  char* As = lds;
  char* Bs = lds + 3 * 8192;

  int tid = threadIdx.x, wave = tid >> 6, lane = tid & 63;
  int ntiles = N >> 7;
  int nwg = (M >> 7) * ntiles;
  int bid = xcd_swz(blockIdx.x, nwg);    // mt-adjacent (nt=0,1) pairs share A-panel
  int mt = bid / ntiles, nt = bid - (bid / ntiles) * ntiles;
  int r16 = lane & 15, kg = lane >> 4;
  int wm = wave >> 1, wn = wave & 1;

  const unsigned short* Bpanel = WS + (size_t)nt * (NT * 512 * 8);
  const unsigned short* Apanel = Av + (size_t)mt * (NT * 512 * 8);

  f32x4 acc[4][4] = {};

  auto stageB = [&](int s) {
    char* Bd = Bs + (s % 3) * 8192;
    const unsigned short* sp = Bpanel + (size_t)s * 512 * 8;
#pragma unroll
    for (int j = 0; j < 2; j++) {
      int f = (j * 4 + wave) * 64 + lane;
      gload16(sp + f * 8, Bd + f * 16);
    }
  };
  auto stageA16 = [&](int s) {
    char* Ad = As + (s % 3) * 8192;
    const unsigned short* sp = Apanel + (size_t)s * 512 * 8;
#pragma unroll
    for (int j = 0; j < 2; j++) {
      int f = (j * 4 + wave) * 64 + lane;
      gload16(sp + f * 8, Ad + f * 16);
    }
  };
  auto compute = [&](int s) {
    const char* Ad = As + (s % 3) * 8192;
    const char* Bd = Bs + (s % 3) * 8192;
    bf16x8 af[4], bq[4];
#pragma unroll
    for (int mi = 0; mi < 4; mi++) {
      int row = wm * 64 + mi * 16 + r16;
      af[mi] = *(const bf16x8*)(Ad + ((kg * 128 + row) << 4));
    }
#pragma unroll
    for (int ni = 0; ni < 4; ni++) {
      int row = wn * 64 + ni * 16 + r16;
      bq[ni] = *(const bf16x8*)(Bd + ((kg * 128 + row) << 4));
    }
#pragma unroll
    for (int mi = 0; mi < 4; mi++)
#pragma unroll
      for (int ni = 0; ni < 4; ni++)
        acc[mi][ni] = __builtin_amdgcn_mfma_f32_16x16x32_bf16(bq[ni], af[mi], acc[mi][ni], 0, 0, 0);
  };

  stageA16(0); stageB(0); stageA16(1); stageB(1);
  asm volatile("s_waitcnt vmcnt(%0)" :: "i"(STEADY) : "memory");
  pipe_barrier();

  auto step = [&](auto TC) {
    constexpr int t = decltype(TC)::v;
    if constexpr (t + 2 < NT) { stageA16(t + 2); stageB(t + 2); }
    compute(t);
    if constexpr (t + 1 < NT) {
      if constexpr (t + 2 < NT)
        asm volatile("s_waitcnt vmcnt(%0)" :: "i"(STEADY) : "memory");
      else
        asm volatile("s_waitcnt vmcnt(0)" ::: "memory");
      pipe_barrier();
    }
  };
  step(IC<0>{}); step(IC<1>{}); step(IC<2>{}); step(IC<3>{});
  step(IC<4>{}); step(IC<5>{}); step(IC<6>{}); step(IC<7>{});

  int rowBase = mt * 128 + wm * 64;
  int colBase = nt * 128 + wn * 64;
#pragma unroll
  for (int ni = 0; ni < 4; ni++) {
    int col = colBase + ni * 16 + kg * 4;
    f32x4 bs = *(const f32x4*)(bias + col);
#pragma unroll
    for (int mi = 0; mi < 4; mi++) {
      int row = rowBase + mi * 16 + r16;
      f32x4 v = acc[mi][ni] + bs;
      *(f32x4*)(C + (size_t)row * N + col) = v;
    }
  }
}

// ---------------- sampling (R11 verbatim): 16-gather MLP + b-locality swizzle --
__global__ __launch_bounds__(256, 3) void sample_k(const float* __restrict__ offattn, // [MQ,384]
                                                   const float* __restrict__ refp,    // [B,Q,4,2]
                                                   const unsigned short* __restrict__ value,
                                                   unsigned short* __restrict__ interS) {
  int orig = blockIdx.x;
  int sb = (orig & 7) * 250 + (orig >> 3);   // bijective (2000 % 8 == 0)
  int t  = sb * 256 + threadIdx.x;
  int bq = t >> 5;
  int h  = (t >> 2) & 7;
  int c0 = (t & 3) << 3;
  int b  = bq / QQ;

  const float* base = offattn + (size_t)bq * 384;

  float lg[16];
  const float4* ab4 = (const float4*)(base + 256 + h * 16);
#pragma unroll
  for (int i = 0; i < 4; i++) {
    float4 v = ab4[i];
    lg[4*i] = v.x; lg[4*i+1] = v.y; lg[4*i+2] = v.z; lg[4*i+3] = v.w;
  }
  float m = -1e30f;
#pragma unroll
  for (int i = 0; i < 16; i++) m = fmaxf(m, lg[i]);
  float s = 0.f;
#pragma unroll
  for (int i = 0; i < 16; i++) { lg[i] = __expf(lg[i] - m); s += lg[i]; }
  float inv = 1.0f / s;

  float4 r01 = ((const float4*)(refp + (size_t)bq * 8))[0];
  float4 r23 = ((const float4*)(refp + (size_t)bq * 8))[1];
  float rxs[4] = {r01.x, r01.z, r23.x, r23.z};
  float rys[4] = {r01.y, r01.w, r23.y, r23.w};

  const unsigned short* vb = value + (size_t)b * (LTOTAL * 256) + h * 32 + c0;
  const int startL[4] = {0, 4096, 5120, 5376};

  float acc[8] = {};
#pragma unroll
  for (int lvl = 0; lvl < 4; lvl++) {
    int   Wi = 64 >> lvl;
    float Wf = (float)Wi;
    float px = rxs[lvl] * Wf - 0.5f;
    float py = rys[lvl] * Wf - 0.5f;
    const unsigned short* vl = vb + (size_t)startL[lvl] * 256;

    const float4* ob4 = (const float4*)(base + h * 32 + lvl * 8);
    float4 o01 = ob4[0], o23 = ob4[1];
    float oxs[4] = {o01.x, o01.z, o23.x, o23.z};
    float oys[4] = {o01.y, o01.w, o23.y, o23.w};

    float cw[16];
    int   coff[16];
#pragma unroll
    for (int pt = 0; pt < 4; pt++) {
      float wa = lg[lvl * 4 + pt] * inv;
      float x = px + oxs[pt];
      float y = py + oys[pt];
      float xf = floorf(x), yf = floorf(y);
      float lx = x - xf, ly = y - yf;
      int x0 = (int)xf, y0 = (int)yf;
      float wx[2] = {1.f - lx, lx};
      float wy[2] = {1.f - ly, ly};
#pragma unroll
      for (int cy = 0; cy < 2; cy++) {
        int Y = y0 + cy;
        bool vy = (unsigned)Y < (unsigned)Wi;
        int Yc = min(max(Y, 0), Wi - 1);
#pragma unroll
        for (int cx = 0; cx < 2; cx++) {
          int X = x0 + cx;
          bool vx = (unsigned)X < (unsigned)Wi;
          int Xc = min(max(X, 0), Wi - 1);
          int c = pt * 4 + cy * 2 + cx;
          cw[c]   = (vx && vy) ? wa * wy[cy] * wx[cx] : 0.f;
          coff[c] = (Yc * Wi + Xc) * 256;
        }
      }
    }
    uint4 raw[16];
#pragma unroll
    for (int c = 0; c < 16; c++) raw[c] = *(const uint4*)(vl + coff[c]);
#pragma unroll
    for (int c = 0; c < 16; c++) {
      float w = cw[c];
      acc[0] += w * b2f_lo(raw[c].x); acc[1] += w * b2f_hi(raw[c].x);
      acc[2] += w * b2f_lo(raw[c].y); acc[3] += w * b2f_hi(raw[c].y);
      acc[4] += w * b2f_lo(raw[c].z); acc[5] += w * b2f_hi(raw[c].z);
      acc[6] += w * b2f_lo(raw[c].w); acc[7] += w * b2f_hi(raw[c].w);
    }
  }

  unsigned o0 = f2bf(acc[0]) | ((unsigned)f2bf(acc[1]) << 16);
  unsigned o1 = f2bf(acc[2]) | ((unsigned)f2bf(acc[3]) << 16);
  unsigned o2 = f2bf(acc[4]) | ((unsigned)f2bf(acc[5]) << 16);
  unsigned o3 = f2bf(acc[6]) | ((unsigned)f2bf(acc[7]) << 16);
  uint4 st = {o0, o1, o2, o3};

  // staged layout: tile = bq>>7, row = bq&127, stage = h, u = c0>>3
  int mtile = bq >> 7, row = bq & 127;
  size_t goff = (((size_t)(mtile * 8 + h)) * 512 + (c0 >> 3) * 128 + row) * 8;
  *(uint4*)(interS + goff) = st;
}

extern "C" void kernel_launch(void* const* d_in, const int* in_sizes, int n_in,
                              void* d_out, int out_size, void* d_ws, size_t ws_size,
                              hipStream_t stream) {
  const float* query  = (const float*)d_in[0];
  const float* refp   = (const float*)d_in[1];
  const float* inputf = (const float*)d_in[2];
  const float* Wv   = (const float*)d_in[5];
  const float* bv   = (const float*)d_in[6];
  const float* Wo   = (const float*)d_in[7];
  const float* bo   = (const float*)d_in[8];
  const float* Wa   = (const float*)d_in[9];
  const float* ba   = (const float*)d_in[10];
  const float* Wout = (const float*)d_in[11];
  const float* bout = (const float*)d_in[12];

  char* p = (char*)d_ws;
  auto alloc = [&](size_t bytes) -> char* {
    char* r = p;
    p += (bytes + 255) & ~(size_t)255;
    return r;
  };
  unsigned short* val   = (unsigned short*)alloc((size_t)MV * 256 * 2);
  unsigned short* WvS   = (unsigned short*)alloc(2 * 4096 * 8 * 2);
  unsigned short* WcS   = (unsigned short*)alloc(3 * 4096 * 8 * 2);
  unsigned short* WoS   = (unsigned short*)alloc(2 * 4096 * 8 * 2);
  float*          bcat  = (float*)alloc(384 * 4);
  float*          offattn = (float*)alloc((size_t)MQ * 384 * 4);
  unsigned short* interS = (unsigned short*)alloc((size_t)MQ * 256 * 2);

  prep_k<<<114, 256, 0, stream>>>(Wv, Wo, Wa, Wout, bo, ba, WvS, WcS, WoS, bcat);

  // fused: value GEMM (1360 blocks) + offattn GEMM (375 blocks), one dispatch
  gemmf_k<<<NVBLK + NOBLK, 256, 0, stream>>>(inputf, query, WvS, WcS, bv, bcat,
                                             val, offattn);
  // sampling -> interS (staged bf16), b-locality XCD swizzle
  sample_k<<<MQ * 32 / 256, 256, 0, stream>>>(offattn, refp, val, interS);
  // out = interS @ Wout + bout -> fp32 d_out
  gemm3b_k<<<(MQ / 128) * 2, 256, 0, stream>>>(interS, WoS, bout, (float*)d_out,
                                               MQ, 256);
}